// Round 4
// baseline (16039.122 us; speedup 1.0000x reference)
//
#include <hip/hip_runtime.h>
#include <math.h>

// Problem constants
#define N_SP 96      // NV + NH
#define D_EMB 32
#define H_MLP 32
#define NPAIR 9216   // N*N
#define NBT 512      // B*T

// float workspace offsets (floats)
#define WS_F_EMBI  0         // 96*32 (includes +b1)
#define WS_F_EMBJT 3072      // 32*96 (transposed [u][j])
#define WS_F_ALPHA 6144      // 96
#define WS_F_WG    6240      // 5*9216

__device__ __forceinline__ float gelu_f(float x){
  return 0.5f * x * (1.0f + erff(x * 0.70710678118654752440f));
}

// ---- precompute: emb_i(+b1), emb_jT, alpha ----
__global__ void pre1_kernel(const float* __restrict__ emb,
                            const float* __restrict__ w1, const float* __restrict__ b1,
                            const float* __restrict__ har,
                            float* __restrict__ wsf){
  const int n = blockIdx.x;
  const int t = threadIdx.x;           // 64 threads
  const int which = t >> 5, idx = t & 31;
  const float* e = emb + n * D_EMB;
  if (which == 0){
    float acc = b1[idx];
    #pragma unroll
    for (int u = 0; u < D_EMB; u++) acc = fmaf(e[u], w1[(2+u)*H_MLP + idx], acc);
    wsf[WS_F_EMBI + n*H_MLP + idx] = acc;
  } else {
    float acc = 0.f;
    #pragma unroll
    for (int u = 0; u < D_EMB; u++) acc = fmaf(e[u], w1[(2+D_EMB+u)*H_MLP + idx], acc);
    wsf[WS_F_EMBJT + idx*N_SP + n] = acc;   // transposed store [u][j]
  }
  if (t == 0){
    float h = har[n];
    float sp = (h > 20.f) ? h : log1pf(expf(h));
    wsf[WS_F_ALPHA + n] = sp + 0.01f;
  }
}

// ---- precompute wg = form_coefs * sigmoid(gates) ----
__global__ void prewg_kernel(const float* __restrict__ fc, const float* __restrict__ fg,
                             float* __restrict__ wsf){
  int idx = blockIdx.x * 256 + threadIdx.x;
  if (idx < 5 * NPAIR){
    float g = 1.f / (1.f + expf(-fg[idx]));
    wsf[WS_F_WG + idx] = fc[idx] * g;
  }
}

// Emulate numpy einsum f32 dot (SSE baseline, npyv_muladd = mul+add, 4x unroll,
// ASCENDING chain): per-lane l in 0..3:
//   iter1: acc_l = p[12+l] + (p[8+l] + (p[4+l] + p[l]))
//   iter2: acc_l = p[28+l] + (p[24+l] + (p[20+l] + (p[16+l] + acc_l)))
// horizontal (SSE3 hadd): (acc0+acc1)+(acc2+acc3); then f32 division by sqrt(32).
__device__ __forceinline__ float np_score(const float* __restrict__ qi,
                                          const float* __restrict__ kT, int j){
  float p[32];
  #pragma unroll
  for (int d2 = 0; d2 < 32; d2++)
    p[d2] = __fmul_rn(qi[d2], kT[d2*N_SP + j]);
  float acc[4];
  #pragma unroll
  for (int l = 0; l < 4; l++){
    float t = __fadd_rn(p[4+l], p[l]);       // ab1 = p4 + (p0 + 0)
    t = __fadd_rn(p[8+l], t);                // ab2
    t = __fadd_rn(p[12+l], t);               // end unroll-iter 1
    t = __fadd_rn(p[16+l], t);
    t = __fadd_rn(p[20+l], t);
    t = __fadd_rn(p[24+l], t);
    t = __fadd_rn(p[28+l], t);               // end unroll-iter 2
    acc[l] = t;
  }
  float s01 = __fadd_rn(acc[0], acc[1]);
  float s23 = __fadd_rn(acc[2], acc[3]);
  return __fdiv_rn(__fadd_rn(s01, s23), 5.65685424949238019521f);
}

// ---- main: one block per (b,t) ----
__global__ __launch_bounds__(512) void main_kernel(
    const float* __restrict__ state, const float* __restrict__ rvec,
    const float* __restrict__ emb,
    const float* __restrict__ qwg, const float* __restrict__ qbg,
    const float* __restrict__ kwg, const float* __restrict__ kbg,
    const float* __restrict__ w1, const float* __restrict__ w2g,
    const float* __restrict__ b2g, const float* __restrict__ w3g,
    const float* __restrict__ b3g,
    const float* __restrict__ wsf,
    float* __restrict__ out_lr, float* __restrict__ out_attn){

  __shared__ float s_embi[N_SP*H_MLP];
  __shared__ float s_embjT[H_MLP*N_SP];          // [u][j]
  __shared__ float s_w2[H_MLP*H_MLP];
  __shared__ float s_q[N_SP*D_EMB];              // [n][d]
  __shared__ float s_kT[D_EMB*N_SP];             // [d][n]
  __shared__ float s_x[N_SP], s_hol[N_SP];
  __shared__ float s_wxi[H_MLP], s_wxj[H_MLP], s_b2[H_MLP], s_w3[H_MLP];

  const int tid = threadIdx.x;
  const int bt  = blockIdx.x;

  for (int idx = tid; idx < N_SP*H_MLP; idx += 512){
    s_embi[idx]  = wsf[WS_F_EMBI  + idx];
    s_embjT[idx] = wsf[WS_F_EMBJT + idx];
  }
  for (int idx = tid; idx < H_MLP*H_MLP; idx += 512) s_w2[idx] = w2g[idx];
  if (tid < N_SP){
    float x = state[bt*N_SP + tid];
    s_x[tid] = x;
    float al = wsf[WS_F_ALPHA + tid];
    s_hol[tid] = x / (1.f + al * x);
  }
  if (tid >= 128 && tid < 160){
    int u = tid - 128;
    s_wxi[u] = w1[u];
    s_wxj[u] = w1[H_MLP + u];
    s_b2[u]  = b2g[u];
    s_w3[u]  = w3g[u];
  }
  __syncthreads();

  // Phase 0: q, kT in f32, BLAS-sgemm order: sequential FMA over the 33
  // feature rows ascending (x term first, then 32 emb terms), bias added last.
  for (int t = tid; t < N_SP*D_EMB; t += 512){
    const int n = t >> 5, d2 = t & 31;
    const float* e = emb + n*D_EMB;
    const float xn = s_x[n];
    float aq = __fmul_rn(xn, qwg[d2]);
    float ak = __fmul_rn(xn, kwg[d2]);
    #pragma unroll
    for (int u = 0; u < D_EMB; u++){
      aq = fmaf(e[u], qwg[(1+u)*D_EMB + d2], aq);
      ak = fmaf(e[u], kwg[(1+u)*D_EMB + d2], ak);
    }
    aq = __fadd_rn(aq, qbg[d2]);
    ak = __fadd_rn(ak, kbg[d2]);
    s_q[t] = aq;
    s_kT[d2*N_SP + n] = ak;
  }

  const float b3v = b3g[0];
  const float* wg = wsf + WS_F_WG;
  float* g_ms = out_attn + (size_t)bt * NPAIR;   // msgs staged in attn output

  // Phase 1: msgs (incl. pairwise MLP f4) -> global (attn buffer)
  for (int p = tid; p < NPAIR; p += 512){
    const int i = p / N_SP;
    const int j = p - i * N_SP;
    const float xi = s_x[i], xj = s_x[j], hj = s_hol[j];

    float h1[H_MLP];
    #pragma unroll
    for (int u = 0; u < H_MLP; u++){
      float v = fmaf(xi, s_wxi[u], fmaf(xj, s_wxj[u], s_embi[i*H_MLP+u] + s_embjT[u*N_SP+j]));
      h1[u] = gelu_f(v);
    }
    float h2[H_MLP];
    #pragma unroll
    for (int v = 0; v < H_MLP; v++) h2[v] = s_b2[v];
    #pragma unroll
    for (int u = 0; u < H_MLP; u++){
      const float a = h1[u];
      const float4* wrow = (const float4*)(&s_w2[u*H_MLP]);
      #pragma unroll
      for (int q = 0; q < 8; q++){
        float4 wv = wrow[q];
        h2[4*q+0] = fmaf(a, wv.x, h2[4*q+0]);
        h2[4*q+1] = fmaf(a, wv.y, h2[4*q+1]);
        h2[4*q+2] = fmaf(a, wv.z, h2[4*q+2]);
        h2[4*q+3] = fmaf(a, wv.w, h2[4*q+3]);
      }
    }
    float f4 = b3v;
    #pragma unroll
    for (int v = 0; v < H_MLP; v++) f4 = fmaf(gelu_f(h2[v]), s_w3[v], f4);

    float msg = wg[p]         * xj
              + wg[NPAIR+p]   * (xi*xj)
              + wg[2*NPAIR+p] * hj
              + wg[3*NPAIR+p] * (xi*hj)
              + wg[4*NPAIR+p] * f4;
    g_ms[p] = msg;
  }
  __syncthreads();   // covers s_q/s_kT and g_ms visibility

  // Phase 2: per-row scores via numpy-einsum emulation, exact top-8 threshold,
  // masked softmax, aggregate. attn overwrites msgs in-place.
  const int wave = tid >> 6, lane = tid & 63;
  const float NEGINF = -__builtin_inff();

  for (int i = wave; i < N_SP; i += 8){
    const float* qi = s_q + i*D_EMB;
    float v0 = np_score(qi, s_kT, lane);
    float v1 = NEGINF;
    if (lane < 32) v1 = np_score(qi, s_kT, 64 + lane);

    // exact top-8 by iterative max extraction (one instance removed per iter)
    float a0 = v0, a1 = v1, thresh = 0.f, m0v = 0.f;
    for (int it = 0; it < 8; ++it){
      float m = fmaxf(a0, a1);
      #pragma unroll
      for (int off = 32; off; off >>= 1) m = fmaxf(m, __shfl_xor(m, off));
      if (it == 0) m0v = m;
      thresh = m;
      unsigned long long ball = __ballot((a0 == m) || (a1 == m));
      int first = __ffsll(ball) - 1;
      if (lane == first){
        if (a0 == m) a0 = NEGINF; else a1 = NEGINF;
      }
    }

    float e0 = (v0 >= thresh) ? expf(v0 - m0v) : 0.f;
    float e1 = 0.f;
    if (lane < 32 && v1 >= thresh) e1 = expf(v1 - m0v);

    float* mrow = out_attn + (size_t)(bt*N_SP + i) * N_SP;  // msgs row -> attn row
    float num = e0 * mrow[lane];
    if (lane < 32) num += e1 * mrow[64 + lane];
    float den = e0 + e1;
    #pragma unroll
    for (int off = 32; off; off >>= 1){
      den += __shfl_xor(den, off);
      num += __shfl_xor(num, off);
    }
    float inv = 1.0f / den;
    mrow[lane] = e0 * inv;
    if (lane < 32) mrow[64 + lane] = e1 * inv;
    if (lane == 0) out_lr[bt*N_SP + i] = rvec[i] + num * inv;
  }
}

extern "C" void kernel_launch(void* const* d_in, const int* in_sizes, int n_in,
                              void* d_out, int out_size, void* d_ws, size_t ws_size,
                              hipStream_t stream){
  const float* state = (const float*)d_in[0];
  const float* emb   = (const float*)d_in[1];
  const float* qw    = (const float*)d_in[2];
  const float* qb    = (const float*)d_in[3];
  const float* kw    = (const float*)d_in[4];
  const float* kb    = (const float*)d_in[5];
  const float* fc    = (const float*)d_in[6];
  const float* fg    = (const float*)d_in[7];
  const float* har   = (const float*)d_in[8];
  const float* w1    = (const float*)d_in[9];
  const float* b1    = (const float*)d_in[10];
  const float* w2    = (const float*)d_in[11];
  const float* b2    = (const float*)d_in[12];
  const float* w3    = (const float*)d_in[13];
  const float* b3    = (const float*)d_in[14];
  const float* rv    = (const float*)d_in[15];

  float* wsf = (float*)d_ws;
  float* out_lr   = (float*)d_out;
  float* out_attn = out_lr + NBT * N_SP;

  hipLaunchKernelGGL(pre1_kernel, dim3(N_SP), dim3(64), 0, stream,
                     emb, w1, b1, har, wsf);
  hipLaunchKernelGGL(prewg_kernel, dim3(180), dim3(256), 0, stream, fc, fg, wsf);
  hipLaunchKernelGGL(main_kernel, dim3(NBT), dim3(512), 0, stream,
                     state, rv, emb, qw, qb, kw, kb, w1, w2, b2, w3, b3,
                     wsf, out_lr, out_attn);
}

// Round 5
// 259.431 us; speedup vs baseline: 61.8242x; 61.8242x over previous
//
#include <hip/hip_runtime.h>
#include <math.h>

// Problem constants
#define N_SP 96      // NV + NH
#define D_EMB 32
#define H_MLP 32
#define NPAIR 9216   // N*N
#define NBT 512      // B*T

// float workspace offsets (floats)
#define WS_F_EMBI  0         // 96*32 (includes +b1)
#define WS_F_EMBJT 3072      // 32*97 (transposed [u][j], row stride 97)
#define WS_F_ALPHA 6176      // 96
#define WS_F_WG    6272      // 5*9216

typedef __attribute__((ext_vector_type(8))) short bf16x8;
typedef __attribute__((ext_vector_type(4))) float f32x4;

__device__ __forceinline__ float gelu_f(float x){
  return 0.5f * x * (1.0f + erff(x * 0.70710678118654752440f));
}

__device__ __forceinline__ short f2bf(float f){
  unsigned u = __builtin_bit_cast(unsigned, f);
  unsigned r = (u + 0x7FFFu + ((u >> 16) & 1u)) >> 16;
  return (short)r;
}

// ---- precompute: emb_i(+b1), emb_jT (stride 97), alpha ----
__global__ void pre1_kernel(const float* __restrict__ emb,
                            const float* __restrict__ w1, const float* __restrict__ b1,
                            const float* __restrict__ har,
                            float* __restrict__ wsf){
  const int n = blockIdx.x;
  const int t = threadIdx.x;           // 64 threads
  const int which = t >> 5, idx = t & 31;
  const float* e = emb + n * D_EMB;
  if (which == 0){
    float acc = b1[idx];
    #pragma unroll
    for (int u = 0; u < D_EMB; u++) acc = fmaf(e[u], w1[(2+u)*H_MLP + idx], acc);
    wsf[WS_F_EMBI + n*H_MLP + idx] = acc;
  } else {
    float acc = 0.f;
    #pragma unroll
    for (int u = 0; u < D_EMB; u++) acc = fmaf(e[u], w1[(2+D_EMB+u)*H_MLP + idx], acc);
    wsf[WS_F_EMBJT + idx*97 + n] = acc;   // transposed store [u][j], stride 97
  }
  if (t == 0){
    float h = har[n];
    float sp = (h > 20.f) ? h : log1pf(expf(h));
    wsf[WS_F_ALPHA + n] = sp + 0.01f;
  }
}

// ---- precompute wg = form_coefs * sigmoid(gates) ----
__global__ void prewg_kernel(const float* __restrict__ fc, const float* __restrict__ fg,
                             float* __restrict__ wsf){
  int idx = blockIdx.x * 256 + threadIdx.x;
  if (idx < 5 * NPAIR){
    float g = 1.f / (1.f + expf(-fg[idx]));
    wsf[WS_F_WG + idx] = fc[idx] * g;
  }
}

// Emulate numpy einsum f32 dot (SSE baseline, mul+add, 4x unroll, ascending
// chain), horizontal (acc0+acc1)+(acc2+acc3), then f32 division by sqrt(32).
// DO NOT TOUCH — bit-matched to the np reference (topk razor rows).
__device__ __forceinline__ float np_score(const float* __restrict__ qi,
                                          const float* __restrict__ kT, int j){
  float p[32];
  #pragma unroll
  for (int d2 = 0; d2 < 32; d2++)
    p[d2] = __fmul_rn(qi[d2], kT[d2*N_SP + j]);
  float acc[4];
  #pragma unroll
  for (int l = 0; l < 4; l++){
    float t = __fadd_rn(p[4+l], p[l]);
    t = __fadd_rn(p[8+l], t);
    t = __fadd_rn(p[12+l], t);
    t = __fadd_rn(p[16+l], t);
    t = __fadd_rn(p[20+l], t);
    t = __fadd_rn(p[24+l], t);
    t = __fadd_rn(p[28+l], t);
    acc[l] = t;
  }
  float s01 = __fadd_rn(acc[0], acc[1]);
  float s23 = __fadd_rn(acc[2], acc[3]);
  return __fdiv_rn(__fadd_rn(s01, s23), 5.65685424949238019521f);
}

// ---- main: one block per (b,t) ----
__global__ __launch_bounds__(512) void main_kernel(
    const float* __restrict__ state, const float* __restrict__ rvec,
    const float* __restrict__ emb,
    const float* __restrict__ qwg, const float* __restrict__ qbg,
    const float* __restrict__ kwg, const float* __restrict__ kbg,
    const float* __restrict__ w1, const float* __restrict__ w2g,
    const float* __restrict__ b2g, const float* __restrict__ w3g,
    const float* __restrict__ b3g,
    const float* __restrict__ wsf,
    float* __restrict__ out_lr, float* __restrict__ out_attn){

  __shared__ __align__(16) float s_embi[N_SP*H_MLP];
  __shared__ float s_embjT[H_MLP*97];            // [u][j], stride 97 (bank-spread)
  __shared__ __align__(16) float s_q[N_SP*D_EMB];   // [n][d]
  __shared__ float s_kT[D_EMB*N_SP];             // [d][n]
  __shared__ float s_x[N_SP], s_hol[N_SP];
  __shared__ __align__(16) float s_wxi[H_MLP];
  __shared__ __align__(16) float s_wxj[H_MLP];
  __shared__ float s_b2[H_MLP], s_w3[H_MLP];

  const int tid = threadIdx.x;
  const int bt  = blockIdx.x;
  const int wave = tid >> 6, lane = tid & 63;

  for (int idx = tid; idx < N_SP*H_MLP; idx += 512) s_embi[idx] = wsf[WS_F_EMBI + idx];
  for (int idx = tid; idx < H_MLP*97; idx += 512)   s_embjT[idx] = wsf[WS_F_EMBJT + idx];
  if (tid < N_SP){
    float x = state[bt*N_SP + tid];
    s_x[tid] = x;
    float al = wsf[WS_F_ALPHA + tid];
    s_hol[tid] = x / (1.f + al * x);
  }
  if (tid >= 128 && tid < 160){
    int u = tid - 128;
    s_wxi[u] = w1[u];
    s_wxj[u] = w1[H_MLP + u];
    s_b2[u]  = b2g[u];
    s_w3[u]  = w3g[u];
  }
  __syncthreads();

  // Phase 0 (UNCHANGED, bit-exact feed of phase 2): q, kT in f32, BLAS order.
  for (int t = tid; t < N_SP*D_EMB; t += 512){
    const int n = t >> 5, d2 = t & 31;
    const float* e = emb + n*D_EMB;
    const float xn = s_x[n];
    float aq = __fmul_rn(xn, qwg[d2]);
    float ak = __fmul_rn(xn, kwg[d2]);
    #pragma unroll
    for (int u = 0; u < D_EMB; u++){
      aq = fmaf(e[u], qwg[(1+u)*D_EMB + d2], aq);
      ak = fmaf(e[u], kwg[(1+u)*D_EMB + d2], ak);
    }
    aq = __fadd_rn(aq, qbg[d2]);
    ak = __fadd_rn(ak, kbg[d2]);
    s_q[t] = aq;
    s_kT[d2*N_SP + n] = ak;
  }

  const float b3v = b3g[0];
  const float* wg = wsf + WS_F_WG;
  float* g_ms = out_attn + (size_t)bt * NPAIR;   // msgs staged in attn output

  // Build register-resident B fragments for w2 (constant per kernel).
  // B layout (16x16x32 bf16): lane holds B[k=(lane>>4)*8+e][col=lane&15].
  const int l15 = lane & 15;
  const int kb  = (lane >> 4) * 8;
  bf16x8 bfrag0, bfrag1;
  #pragma unroll
  for (int e = 0; e < 8; e++){
    bfrag0[e] = f2bf(w2g[(kb+e)*H_MLP + l15]);
    bfrag1[e] = f2bf(w2g[(kb+e)*H_MLP + 16 + l15]);
  }
  const float bias0 = b2g[l15],      bias1 = b2g[16 + l15];
  const float w3v0  = w3g[l15],      w3v1  = w3g[16 + l15];

  // Phase 1: msgs via MFMA pairwise MLP. Each wave: rows 12w..12w+11,
  // 6 batches of 16 j's per row -> 72 batches of 16 pairs.
  for (int t = 0; t < 72; t++){
    const int i  = 12*wave + t/6;
    const int j0 = 16*(t - 6*(t/6));
    const int jl = j0 + l15;                 // this lane's A-row pair j
    const float xi = s_x[i];
    const float xj = s_x[jl];

    // A fragment: lane holds h1[row=l15][k=kb+e] (post-gelu, bf16)
    const float4 ei0 = *(const float4*)&s_embi[i*H_MLP + kb];
    const float4 ei1 = *(const float4*)&s_embi[i*H_MLP + kb + 4];
    const float4 wi0 = *(const float4*)&s_wxi[kb];
    const float4 wi1 = *(const float4*)&s_wxi[kb + 4];
    const float4 wj0 = *(const float4*)&s_wxj[kb];
    const float4 wj1 = *(const float4*)&s_wxj[kb + 4];
    bf16x8 afrag;
    #pragma unroll
    for (int e = 0; e < 8; e++){
      const float eiv = (e < 4) ? ((const float*)&ei0)[e]   : ((const float*)&ei1)[e-4];
      const float wiv = (e < 4) ? ((const float*)&wi0)[e]   : ((const float*)&wi1)[e-4];
      const float wjv = (e < 4) ? ((const float*)&wj0)[e]   : ((const float*)&wj1)[e-4];
      const float pre = fmaf(xi, wiv, fmaf(xj, wjv, eiv + s_embjT[(kb+e)*97 + jl]));
      afrag[e] = f2bf(gelu_f(pre));
    }

    f32x4 acc0 = {0.f,0.f,0.f,0.f};
    f32x4 acc1 = {0.f,0.f,0.f,0.f};
    acc0 = __builtin_amdgcn_mfma_f32_16x16x32_bf16(afrag, bfrag0, acc0, 0, 0, 0);
    acc1 = __builtin_amdgcn_mfma_f32_16x16x32_bf16(afrag, bfrag1, acc1, 0, 0, 0);

    // Epilogue: C row=(lane>>4)*4+r, col=l15. f4 partial per lane, 16-lane reduce.
    #pragma unroll
    for (int r = 0; r < 4; r++){
      float pr = gelu_f(acc0[r] + bias0) * w3v0 + gelu_f(acc1[r] + bias1) * w3v1;
      #pragma unroll
      for (int off = 1; off < 16; off <<= 1) pr += __shfl_xor(pr, off);
      if (l15 == r){
        const int P = 4*(lane >> 4) + r;
        const int j = j0 + P;
        const int p = i*N_SP + j;
        const float xjp = s_x[j], hjp = s_hol[j];
        const float f4 = pr + b3v;
        const float msg = wg[p]         * xjp
                        + wg[NPAIR+p]   * (xi*xjp)
                        + wg[2*NPAIR+p] * hjp
                        + wg[3*NPAIR+p] * (xi*hjp)
                        + wg[4*NPAIR+p] * f4;
        g_ms[p] = msg;
      }
    }
  }
  __syncthreads();   // covers s_q/s_kT and g_ms visibility

  // Phase 2 (UNCHANGED, bit-exact): scores via numpy-einsum emulation,
  // exact top-8 threshold, masked softmax, aggregate. attn overwrites msgs.
  const float NEGINF = -__builtin_inff();

  for (int i = wave; i < N_SP; i += 8){
    const float* qi = s_q + i*D_EMB;
    float v0 = np_score(qi, s_kT, lane);
    float v1 = NEGINF;
    if (lane < 32) v1 = np_score(qi, s_kT, 64 + lane);

    float a0 = v0, a1 = v1, thresh = 0.f, m0v = 0.f;
    for (int it = 0; it < 8; ++it){
      float m = fmaxf(a0, a1);
      #pragma unroll
      for (int off = 32; off; off >>= 1) m = fmaxf(m, __shfl_xor(m, off));
      if (it == 0) m0v = m;
      thresh = m;
      unsigned long long ball = __ballot((a0 == m) || (a1 == m));
      int first = __ffsll(ball) - 1;
      if (lane == first){
        if (a0 == m) a0 = NEGINF; else a1 = NEGINF;
      }
    }

    float e0 = (v0 >= thresh) ? expf(v0 - m0v) : 0.f;
    float e1 = 0.f;
    if (lane < 32 && v1 >= thresh) e1 = expf(v1 - m0v);

    float* mrow = out_attn + (size_t)(bt*N_SP + i) * N_SP;
    float num = e0 * mrow[lane];
    if (lane < 32) num += e1 * mrow[64 + lane];
    float den = e0 + e1;
    #pragma unroll
    for (int off = 32; off; off >>= 1){
      den += __shfl_xor(den, off);
      num += __shfl_xor(num, off);
    }
    float inv = 1.0f / den;
    mrow[lane] = e0 * inv;
    if (lane < 32) mrow[64 + lane] = e1 * inv;
    if (lane == 0) out_lr[bt*N_SP + i] = rvec[i] + num * inv;
  }
}

extern "C" void kernel_launch(void* const* d_in, const int* in_sizes, int n_in,
                              void* d_out, int out_size, void* d_ws, size_t ws_size,
                              hipStream_t stream){
  const float* state = (const float*)d_in[0];
  const float* emb   = (const float*)d_in[1];
  const float* qw    = (const float*)d_in[2];
  const float* qb    = (const float*)d_in[3];
  const float* kw    = (const float*)d_in[4];
  const float* kb    = (const float*)d_in[5];
  const float* fc    = (const float*)d_in[6];
  const float* fg    = (const float*)d_in[7];
  const float* har   = (const float*)d_in[8];
  const float* w1    = (const float*)d_in[9];
  const float* b1    = (const float*)d_in[10];
  const float* w2    = (const float*)d_in[11];
  const float* b2    = (const float*)d_in[12];
  const float* w3    = (const float*)d_in[13];
  const float* b3    = (const float*)d_in[14];
  const float* rv    = (const float*)d_in[15];

  float* wsf = (float*)d_ws;
  float* out_lr   = (float*)d_out;
  float* out_attn = out_lr + NBT * N_SP;

  hipLaunchKernelGGL(pre1_kernel, dim3(N_SP), dim3(64), 0, stream,
                     emb, w1, b1, har, wsf);
  hipLaunchKernelGGL(prewg_kernel, dim3(180), dim3(256), 0, stream, fc, fg, wsf);
  hipLaunchKernelGGL(main_kernel, dim3(NBT), dim3(512), 0, stream,
                     state, rv, emb, qw, qb, kw, kb, w1, w2, b2, w3, b3,
                     wsf, out_lr, out_attn);
}

// Round 6
// 236.206 us; speedup vs baseline: 67.9032x; 1.0983x over previous
//
#include <hip/hip_runtime.h>
#include <math.h>

// Problem constants
#define N_SP 96      // NV + NH
#define D_EMB 32
#define H_MLP 32
#define NPAIR 9216   // N*N
#define NBT 512      // B*T

// float workspace offsets (floats)
#define WS_F_EMBI  0         // 96*32 (includes +b1)
#define WS_F_EMBJT 3072      // 32*97 (transposed [u][j], row stride 97)
#define WS_F_ALPHA 6176      // 96
#define WS_F_WG    6272      // 5*9216

typedef __attribute__((ext_vector_type(8))) short bf16x8;
typedef __attribute__((ext_vector_type(4))) float f32x4;

// Fast gelu (tanh form) via v_exp_f32 + v_rcp_f32:
// gelu(x) ~= x * sigmoid(2*0.7978845608*(x + 0.044715 x^3))
//          = x * rcp(1 + exp2(x*(c0 + c1*x^2)))
// c0 = -2*log2(e)*0.7978845608, c1 = -2*log2(e)*0.0356774081
// max abs deviation from exact erf-gelu ~3e-4 (fine: msgs path only).
__device__ __forceinline__ float gelu_fast(float x){
  float x2 = x * x;
  float z  = x * fmaf(x2, -0.1029438824f, -2.3022077325f);
  float e  = __builtin_amdgcn_exp2f(z);
  return x * __builtin_amdgcn_rcpf(1.0f + e);
}

__device__ __forceinline__ short f2bf(float f){
  unsigned u = __builtin_bit_cast(unsigned, f);
  unsigned r = (u + 0x7FFFu + ((u >> 16) & 1u)) >> 16;
  return (short)r;
}

// ---- precompute: emb_i(+b1), emb_jT (stride 97), alpha ----
__global__ void pre1_kernel(const float* __restrict__ emb,
                            const float* __restrict__ w1, const float* __restrict__ b1,
                            const float* __restrict__ har,
                            float* __restrict__ wsf){
  const int n = blockIdx.x;
  const int t = threadIdx.x;           // 64 threads
  const int which = t >> 5, idx = t & 31;
  const float* e = emb + n * D_EMB;
  if (which == 0){
    float acc = b1[idx];
    #pragma unroll
    for (int u = 0; u < D_EMB; u++) acc = fmaf(e[u], w1[(2+u)*H_MLP + idx], acc);
    wsf[WS_F_EMBI + n*H_MLP + idx] = acc;
  } else {
    float acc = 0.f;
    #pragma unroll
    for (int u = 0; u < D_EMB; u++) acc = fmaf(e[u], w1[(2+D_EMB+u)*H_MLP + idx], acc);
    wsf[WS_F_EMBJT + idx*97 + n] = acc;   // transposed store [u][j], stride 97
  }
  if (t == 0){
    float h = har[n];
    float sp = (h > 20.f) ? h : log1pf(expf(h));
    wsf[WS_F_ALPHA + n] = sp + 0.01f;
  }
}

// ---- precompute wg = form_coefs * sigmoid(gates) ----
__global__ void prewg_kernel(const float* __restrict__ fc, const float* __restrict__ fg,
                             float* __restrict__ wsf){
  int idx = blockIdx.x * 256 + threadIdx.x;
  if (idx < 5 * NPAIR){
    float g = 1.f / (1.f + expf(-fg[idx]));
    wsf[WS_F_WG + idx] = fc[idx] * g;
  }
}

// Emulate numpy einsum f32 dot (SSE baseline, mul+add, 4x unroll, ascending
// chain), horizontal (acc0+acc1)+(acc2+acc3), then f32 division by sqrt(32).
// DO NOT TOUCH — bit-matched to the np reference (topk razor rows).
__device__ __forceinline__ float np_score(const float* __restrict__ qi,
                                          const float* __restrict__ kT, int j){
  float p[32];
  #pragma unroll
  for (int d2 = 0; d2 < 32; d2++)
    p[d2] = __fmul_rn(qi[d2], kT[d2*N_SP + j]);
  float acc[4];
  #pragma unroll
  for (int l = 0; l < 4; l++){
    float t = __fadd_rn(p[4+l], p[l]);
    t = __fadd_rn(p[8+l], t);
    t = __fadd_rn(p[12+l], t);
    t = __fadd_rn(p[16+l], t);
    t = __fadd_rn(p[20+l], t);
    t = __fadd_rn(p[24+l], t);
    t = __fadd_rn(p[28+l], t);
    acc[l] = t;
  }
  float s01 = __fadd_rn(acc[0], acc[1]);
  float s23 = __fadd_rn(acc[2], acc[3]);
  return __fdiv_rn(__fadd_rn(s01, s23), 5.65685424949238019521f);
}

// ---- main: one block per (b,t) ----
__global__ __launch_bounds__(512) void main_kernel(
    const float* __restrict__ state, const float* __restrict__ rvec,
    const float* __restrict__ emb,
    const float* __restrict__ qwg, const float* __restrict__ qbg,
    const float* __restrict__ kwg, const float* __restrict__ kbg,
    const float* __restrict__ w1, const float* __restrict__ w2g,
    const float* __restrict__ b2g, const float* __restrict__ w3g,
    const float* __restrict__ b3g,
    const float* __restrict__ wsf,
    float* __restrict__ out_lr, float* __restrict__ out_attn){

  __shared__ __align__(16) float s_embi[N_SP*H_MLP];
  __shared__ float s_embjT[H_MLP*97];            // [u][j], stride 97 (bank-spread)
  __shared__ __align__(16) float s_q[N_SP*D_EMB];   // [n][d]
  __shared__ float s_kT[D_EMB*N_SP];             // [d][n]
  __shared__ float s_x[N_SP], s_hol[N_SP];
  __shared__ __align__(16) float s_wxi[H_MLP];
  __shared__ __align__(16) float s_wxj[H_MLP];
  __shared__ float s_b2[H_MLP], s_w3[H_MLP];

  const int tid = threadIdx.x;
  const int bt  = blockIdx.x;
  const int wave = tid >> 6, lane = tid & 63;

  for (int idx = tid; idx < N_SP*H_MLP; idx += 512) s_embi[idx] = wsf[WS_F_EMBI + idx];
  for (int idx = tid; idx < H_MLP*97; idx += 512)   s_embjT[idx] = wsf[WS_F_EMBJT + idx];
  if (tid < N_SP){
    float x = state[bt*N_SP + tid];
    s_x[tid] = x;
    float al = wsf[WS_F_ALPHA + tid];
    s_hol[tid] = x / (1.f + al * x);
  }
  if (tid >= 128 && tid < 160){
    int u = tid - 128;
    s_wxi[u] = w1[u];
    s_wxj[u] = w1[H_MLP + u];
    s_b2[u]  = b2g[u];
    s_w3[u]  = w3g[u];
  }
  __syncthreads();

  // Phase 0 (UNCHANGED, bit-exact feed of phase 2): q, kT in f32, BLAS order.
  for (int t = tid; t < N_SP*D_EMB; t += 512){
    const int n = t >> 5, d2 = t & 31;
    const float* e = emb + n*D_EMB;
    const float xn = s_x[n];
    float aq = __fmul_rn(xn, qwg[d2]);
    float ak = __fmul_rn(xn, kwg[d2]);
    #pragma unroll
    for (int u = 0; u < D_EMB; u++){
      aq = fmaf(e[u], qwg[(1+u)*D_EMB + d2], aq);
      ak = fmaf(e[u], kwg[(1+u)*D_EMB + d2], ak);
    }
    aq = __fadd_rn(aq, qbg[d2]);
    ak = __fadd_rn(ak, kbg[d2]);
    s_q[t] = aq;
    s_kT[d2*N_SP + n] = ak;
  }

  const float b3v = b3g[0];
  const float* wg = wsf + WS_F_WG;
  float* g_ms = out_attn + (size_t)bt * NPAIR;   // msgs staged in attn output

  // Register-resident B fragments for w2 (constant per kernel).
  // B layout (16x16x32 bf16): lane holds B[k=(lane>>4)*8+e][col=lane&15].
  const int l15 = lane & 15;
  const int kb  = (lane >> 4) * 8;
  bf16x8 bfrag0, bfrag1;
  #pragma unroll
  for (int e = 0; e < 8; e++){
    bfrag0[e] = f2bf(w2g[(kb+e)*H_MLP + l15]);
    bfrag1[e] = f2bf(w2g[(kb+e)*H_MLP + 16 + l15]);
  }
  const float bias0 = b2g[l15],      bias1 = b2g[16 + l15];
  const float w3v0  = w3g[l15],      w3v1  = w3g[16 + l15];

  // Hoist w1 row slices to registers (constant per lane).
  float wi[8], wj[8];
  #pragma unroll
  for (int e = 0; e < 8; e++){ wi[e] = s_wxi[kb+e]; wj[e] = s_wxj[kb+e]; }

  // Phase 1: msgs via MFMA pairwise MLP. Wave owns rows 12w..12w+11;
  // per row, 6 batches of 16 j's.
  for (int ii = 0; ii < 12; ii++){
    const int i  = 12*wave + ii;
    const float xi = s_x[i];
    float base[8];
    #pragma unroll
    for (int e = 0; e < 8; e++)
      base[e] = fmaf(xi, wi[e], s_embi[i*H_MLP + kb + e]);

    for (int jb = 0; jb < 6; jb++){
      const int j0 = 16*jb;
      const int jl = j0 + l15;                 // this lane's A-row pair j
      const float xj = s_x[jl];

      // A fragment: lane holds h1[row=l15][k=kb+e] (post-gelu, bf16)
      bf16x8 afrag;
      #pragma unroll
      for (int e = 0; e < 8; e++){
        float pre = fmaf(xj, wj[e], base[e] + s_embjT[(kb+e)*97 + jl]);
        afrag[e] = f2bf(gelu_fast(pre));
      }

      f32x4 acc0 = {0.f,0.f,0.f,0.f};
      f32x4 acc1 = {0.f,0.f,0.f,0.f};
      acc0 = __builtin_amdgcn_mfma_f32_16x16x32_bf16(afrag, bfrag0, acc0, 0, 0, 0);
      acc1 = __builtin_amdgcn_mfma_f32_16x16x32_bf16(afrag, bfrag1, acc1, 0, 0, 0);

      // Epilogue: C row=(lane>>4)*4+r, col=l15. 16-lane reduce -> f4 -> msg.
      #pragma unroll
      for (int r = 0; r < 4; r++){
        float pr = fmaf(gelu_fast(acc0[r] + bias0), w3v0,
                        gelu_fast(acc1[r] + bias1) * w3v1);
        #pragma unroll
        for (int off = 1; off < 16; off <<= 1) pr += __shfl_xor(pr, off);
        if (l15 == r){
          const int j = j0 + 4*(lane >> 4) + r;
          const int p = i*N_SP + j;
          const float xjp = s_x[j], hjp = s_hol[j];
          const float f4 = pr + b3v;
          const float msg = wg[p]         * xjp
                          + wg[NPAIR+p]   * (xi*xjp)
                          + wg[2*NPAIR+p] * hjp
                          + wg[3*NPAIR+p] * (xi*hjp)
                          + wg[4*NPAIR+p] * f4;
          g_ms[p] = msg;
        }
      }
    }
  }
  __syncthreads();   // covers s_q/s_kT and g_ms visibility

  // Phase 2 (UNCHANGED, bit-exact): scores via numpy-einsum emulation,
  // exact top-8 threshold, masked softmax, aggregate. attn overwrites msgs.
  const float NEGINF = -__builtin_inff();

  for (int i = wave; i < N_SP; i += 8){
    const float* qi = s_q + i*D_EMB;
    float v0 = np_score(qi, s_kT, lane);
    float v1 = NEGINF;
    if (lane < 32) v1 = np_score(qi, s_kT, 64 + lane);

    float a0 = v0, a1 = v1, thresh = 0.f, m0v = 0.f;
    for (int it = 0; it < 8; ++it){
      float m = fmaxf(a0, a1);
      #pragma unroll
      for (int off = 32; off; off >>= 1) m = fmaxf(m, __shfl_xor(m, off));
      if (it == 0) m0v = m;
      thresh = m;
      unsigned long long ball = __ballot((a0 == m) || (a1 == m));
      int first = __ffsll(ball) - 1;
      if (lane == first){
        if (a0 == m) a0 = NEGINF; else a1 = NEGINF;
      }
    }

    float e0 = (v0 >= thresh) ? expf(v0 - m0v) : 0.f;
    float e1 = 0.f;
    if (lane < 32 && v1 >= thresh) e1 = expf(v1 - m0v);

    float* mrow = out_attn + (size_t)(bt*N_SP + i) * N_SP;
    float num = e0 * mrow[lane];
    if (lane < 32) num += e1 * mrow[64 + lane];
    float den = e0 + e1;
    #pragma unroll
    for (int off = 32; off; off >>= 1){
      den += __shfl_xor(den, off);
      num += __shfl_xor(num, off);
    }
    float inv = 1.0f / den;
    mrow[lane] = e0 * inv;
    if (lane < 32) mrow[64 + lane] = e1 * inv;
    if (lane == 0) out_lr[bt*N_SP + i] = rvec[i] + num * inv;
  }
}

extern "C" void kernel_launch(void* const* d_in, const int* in_sizes, int n_in,
                              void* d_out, int out_size, void* d_ws, size_t ws_size,
                              hipStream_t stream){
  const float* state = (const float*)d_in[0];
  const float* emb   = (const float*)d_in[1];
  const float* qw    = (const float*)d_in[2];
  const float* qb    = (const float*)d_in[3];
  const float* kw    = (const float*)d_in[4];
  const float* kb    = (const float*)d_in[5];
  const float* fc    = (const float*)d_in[6];
  const float* fg    = (const float*)d_in[7];
  const float* har   = (const float*)d_in[8];
  const float* w1    = (const float*)d_in[9];
  const float* b1    = (const float*)d_in[10];
  const float* w2    = (const float*)d_in[11];
  const float* b2    = (const float*)d_in[12];
  const float* w3    = (const float*)d_in[13];
  const float* b3    = (const float*)d_in[14];
  const float* rv    = (const float*)d_in[15];

  float* wsf = (float*)d_ws;
  float* out_lr   = (float*)d_out;
  float* out_attn = out_lr + NBT * N_SP;

  hipLaunchKernelGGL(pre1_kernel, dim3(N_SP), dim3(64), 0, stream,
                     emb, w1, b1, har, wsf);
  hipLaunchKernelGGL(prewg_kernel, dim3(180), dim3(256), 0, stream, fc, fg, wsf);
  hipLaunchKernelGGL(main_kernel, dim3(NBT), dim3(512), 0, stream,
                     state, rv, emb, qw, qb, kw, kb, w1, w2, b2, w3, b3,
                     wsf, out_lr, out_attn);
}

// Round 7
// 229.712 us; speedup vs baseline: 69.8228x; 1.0283x over previous
//
#include <hip/hip_runtime.h>
#include <math.h>

// Problem constants
#define N_SP 96      // NV + NH
#define D_EMB 32
#define H_MLP 32
#define NPAIR 9216   // N*N
#define NBT 512      // B*T

// float workspace offsets (floats)
#define WS_F_EMBI  0         // 96*32 (includes +b1)
#define WS_F_EMBJT 3072      // 32*97 (transposed [u][j], row stride 97)
#define WS_F_ALPHA 6176      // 96
#define WS_F_WG4   6272      // 9216*4  (forms 0-3, interleaved float4 per pair)
#define WS_F_WG1   43136     // 9216    (form 4 coef)

typedef __attribute__((ext_vector_type(8))) short bf16x8;
typedef __attribute__((ext_vector_type(4))) float f32x4;

// Fast gelu (tanh form) via v_exp_f32 + v_rcp_f32 (~3e-4 abs dev; msgs path only)
__device__ __forceinline__ float gelu_fast(float x){
  float x2 = x * x;
  float z  = x * fmaf(x2, -0.1029438824f, -2.3022077325f);
  float e  = __builtin_amdgcn_exp2f(z);
  return x * __builtin_amdgcn_rcpf(1.0f + e);
}

__device__ __forceinline__ short f2bf(float f){
  unsigned u = __builtin_bit_cast(unsigned, f);
  unsigned r = (u + 0x7FFFu + ((u >> 16) & 1u)) >> 16;
  return (short)r;
}

// ---- precompute: emb_i(+b1), emb_jT (stride 97), alpha ----
__global__ void pre1_kernel(const float* __restrict__ emb,
                            const float* __restrict__ w1, const float* __restrict__ b1,
                            const float* __restrict__ har,
                            float* __restrict__ wsf){
  const int n = blockIdx.x;
  const int t = threadIdx.x;           // 64 threads
  const int which = t >> 5, idx = t & 31;
  const float* e = emb + n * D_EMB;
  if (which == 0){
    float acc = b1[idx];
    #pragma unroll
    for (int u = 0; u < D_EMB; u++) acc = fmaf(e[u], w1[(2+u)*H_MLP + idx], acc);
    wsf[WS_F_EMBI + n*H_MLP + idx] = acc;
  } else {
    float acc = 0.f;
    #pragma unroll
    for (int u = 0; u < D_EMB; u++) acc = fmaf(e[u], w1[(2+D_EMB+u)*H_MLP + idx], acc);
    wsf[WS_F_EMBJT + idx*97 + n] = acc;   // transposed store [u][j], stride 97
  }
  if (t == 0){
    float h = har[n];
    float sp = (h > 20.f) ? h : log1pf(expf(h));
    wsf[WS_F_ALPHA + n] = sp + 0.01f;
  }
}

// ---- precompute wg = form_coefs * sigmoid(gates), repacked ----
__global__ void prewg_kernel(const float* __restrict__ fc, const float* __restrict__ fg,
                             float* __restrict__ wsf){
  int idx = blockIdx.x * 256 + threadIdx.x;
  if (idx < 5 * NPAIR){
    float g = 1.f / (1.f + expf(-fg[idx]));
    float v = fc[idx] * g;
    int f = idx / NPAIR;
    int p = idx - f * NPAIR;
    if (f < 4) wsf[WS_F_WG4 + 4*p + f] = v;
    else       wsf[WS_F_WG1 + p] = v;
  }
}

// Emulate numpy einsum f32 dot (SSE baseline, mul+add, 4x unroll, ascending
// chain), horizontal (acc0+acc1)+(acc2+acc3), then f32 division by sqrt(32).
// DO NOT TOUCH arithmetic — bit-matched to the np reference (topk razor rows).
// kT row stride is 97 (layout only; values identical).
__device__ __forceinline__ float np_score(const float* __restrict__ qi,
                                          const float* __restrict__ kT, int j){
  float p[32];
  #pragma unroll
  for (int d2 = 0; d2 < 32; d2++)
    p[d2] = __fmul_rn(qi[d2], kT[d2*97 + j]);
  float acc[4];
  #pragma unroll
  for (int l = 0; l < 4; l++){
    float t = __fadd_rn(p[4+l], p[l]);
    t = __fadd_rn(p[8+l], t);
    t = __fadd_rn(p[12+l], t);
    t = __fadd_rn(p[16+l], t);
    t = __fadd_rn(p[20+l], t);
    t = __fadd_rn(p[24+l], t);
    t = __fadd_rn(p[28+l], t);
    acc[l] = t;
  }
  float s01 = __fadd_rn(acc[0], acc[1]);
  float s23 = __fadd_rn(acc[2], acc[3]);
  return __fdiv_rn(__fadd_rn(s01, s23), 5.65685424949238019521f);
}

// ---- main: one block per (b,t) ----
__global__ __launch_bounds__(512) void main_kernel(
    const float* __restrict__ state, const float* __restrict__ rvec,
    const float* __restrict__ emb,
    const float* __restrict__ qwg, const float* __restrict__ qbg,
    const float* __restrict__ kwg, const float* __restrict__ kbg,
    const float* __restrict__ w1, const float* __restrict__ w2g,
    const float* __restrict__ b2g, const float* __restrict__ w3g,
    const float* __restrict__ b3g,
    const float* __restrict__ wsf,
    float* __restrict__ out_lr, float* __restrict__ out_attn){

  __shared__ __align__(16) float s_embi[N_SP*H_MLP];
  __shared__ float s_embjT[H_MLP*97];            // [u][j], stride 97
  __shared__ __align__(16) float s_q[N_SP*D_EMB];   // [n][d]
  __shared__ float s_kT[D_EMB*97];               // [d][n], stride 97
  __shared__ float s_x[N_SP], s_hol[N_SP];
  __shared__ __align__(16) float s_wxi[H_MLP];
  __shared__ __align__(16) float s_wxj[H_MLP];
  __shared__ float s_b2[H_MLP], s_w3[H_MLP];

  const int tid = threadIdx.x;
  const int bt  = blockIdx.x;
  const int wave = tid >> 6, lane = tid & 63;

  for (int idx = tid; idx < N_SP*H_MLP; idx += 512) s_embi[idx] = wsf[WS_F_EMBI + idx];
  for (int idx = tid; idx < H_MLP*97; idx += 512)   s_embjT[idx] = wsf[WS_F_EMBJT + idx];
  if (tid < N_SP){
    float x = state[bt*N_SP + tid];
    s_x[tid] = x;
    float al = wsf[WS_F_ALPHA + tid];
    s_hol[tid] = x / (1.f + al * x);
  }
  if (tid >= 128 && tid < 160){
    int u = tid - 128;
    s_wxi[u] = w1[u];
    s_wxj[u] = w1[H_MLP + u];
    s_b2[u]  = b2g[u];
    s_w3[u]  = w3g[u];
  }
  __syncthreads();

  // Phase 0 (UNCHANGED arithmetic, bit-exact feed of phase 2).
  for (int t = tid; t < N_SP*D_EMB; t += 512){
    const int n = t >> 5, d2 = t & 31;
    const float* e = emb + n*D_EMB;
    const float xn = s_x[n];
    float aq = __fmul_rn(xn, qwg[d2]);
    float ak = __fmul_rn(xn, kwg[d2]);
    #pragma unroll
    for (int u = 0; u < D_EMB; u++){
      aq = fmaf(e[u], qwg[(1+u)*D_EMB + d2], aq);
      ak = fmaf(e[u], kwg[(1+u)*D_EMB + d2], ak);
    }
    aq = __fadd_rn(aq, qbg[d2]);
    ak = __fadd_rn(ak, kbg[d2]);
    s_q[t] = aq;
    s_kT[d2*97 + n] = ak;
  }

  const float b3v = b3g[0];
  const float* wg4 = wsf + WS_F_WG4;
  const float* wg1 = wsf + WS_F_WG1;
  float* g_ms = out_attn + (size_t)bt * NPAIR;   // msgs staged in attn output

  // w2^T as MFMA A-operand fragments (constant). A[row=unit l15][k=kb+e]
  // = w2[k][unit]. frag0: units 0-15, frag1: units 16-31.
  const int l15 = lane & 15;
  const int g16 = lane >> 4;
  const int kb  = g16 * 8;
  bf16x8 w2f0, w2f1;
  #pragma unroll
  for (int e = 0; e < 8; e++){
    w2f0[e] = f2bf(w2g[(kb+e)*H_MLP + l15]);
    w2f1[e] = f2bf(w2g[(kb+e)*H_MLP + 16 + l15]);
  }
  // per-lane b2/w3 for rows v = 4*g16 + r and 16 + 4*g16 + r
  float b2a[4], b2b[4], w3a[4], w3b[4];
  #pragma unroll
  for (int r = 0; r < 4; r++){
    b2a[r] = s_b2[4*g16 + r];      b2b[r] = s_b2[16 + 4*g16 + r];
    w3a[r] = s_w3[4*g16 + r];      w3b[r] = s_w3[16 + 4*g16 + r];
  }
  float wi[8], wj[8];
  #pragma unroll
  for (int e = 0; e < 8; e++){ wi[e] = s_wxi[kb+e]; wj[e] = s_wxj[kb+e]; }

  // Phase 1: msgs via transposed-MFMA pairwise MLP. Wave owns rows 12w..12w+11.
  for (int ii = 0; ii < 12; ii++){
    const int i  = 12*wave + ii;
    const float xi = s_x[i];
    float base[8];
    #pragma unroll
    for (int e = 0; e < 8; e++)
      base[e] = fmaf(xi, wi[e], s_embi[i*H_MLP + kb + e]);

    for (int jb = 0; jb < 6; jb++){
      const int j0 = 16*jb;
      const int jl = j0 + l15;
      const float xj = s_x[jl];

      // early (pre-MFMA) loads for the msg tail: hide global latency
      float4 w4v = {0,0,0,0};
      float  w1v = 0.f, xjp = 0.f, hjp = 0.f;
      if (lane < 16){
        const int p = i*N_SP + j0 + lane;
        w4v = *(const float4*)&wg4[4*p];
        w1v = wg1[p];
        xjp = s_x[j0 + lane];
        hjp = s_hol[j0 + lane];
      }

      // h1 fragment (B-operand): lane holds h1[pair=l15][k=kb+e]
      bf16x8 hfrag;
      #pragma unroll
      for (int e = 0; e < 8; e++){
        float pre = fmaf(xj, wj[e], base[e] + s_embjT[(kb+e)*97 + jl]);
        hfrag[e] = f2bf(gelu_fast(pre));
      }

      f32x4 acc0 = {b2a[0], b2a[1], b2a[2], b2a[3]};
      f32x4 acc1 = {b2b[0], b2b[1], b2b[2], b2b[3]};
      acc0 = __builtin_amdgcn_mfma_f32_16x16x32_bf16(w2f0, hfrag, acc0, 0, 0, 0);
      acc1 = __builtin_amdgcn_mfma_f32_16x16x32_bf16(w2f1, hfrag, acc1, 0, 0, 0);
      // C[v=4*g16+r (+16)][pair=l15] = h2 + b2

      float part = 0.f;
      #pragma unroll
      for (int r = 0; r < 4; r++) part = fmaf(gelu_fast(acc0[r]), w3a[r], part);
      #pragma unroll
      for (int r = 0; r < 4; r++) part = fmaf(gelu_fast(acc1[r]), w3b[r], part);
      part += __shfl_xor(part, 16);
      part += __shfl_xor(part, 32);
      // every lane: part = f4[pair l15] - b3

      if (lane < 16){
        const float f4 = part + b3v;
        const float msg = w4v.x * xjp
                        + w4v.y * (xi*xjp)
                        + w4v.z * hjp
                        + w4v.w * (xi*hjp)
                        + w1v   * f4;
        g_ms[i*N_SP + j0 + lane] = msg;
      }
    }
  }
  __syncthreads();   // covers s_q/s_kT and g_ms visibility

  // Phase 2 (UNCHANGED arithmetic, bit-exact): numpy-emulated scores,
  // exact top-8 threshold, masked softmax, aggregate. attn overwrites msgs.
  const float NEGINF = -__builtin_inff();

  for (int i = wave; i < N_SP; i += 8){
    const float* qi = s_q + i*D_EMB;
    float v0 = np_score(qi, s_kT, lane);
    float v1 = NEGINF;
    if (lane < 32) v1 = np_score(qi, s_kT, 64 + lane);

    float a0 = v0, a1 = v1, thresh = 0.f, m0v = 0.f;
    for (int it = 0; it < 8; ++it){
      float m = fmaxf(a0, a1);
      #pragma unroll
      for (int off = 32; off; off >>= 1) m = fmaxf(m, __shfl_xor(m, off));
      if (it == 0) m0v = m;
      thresh = m;
      unsigned long long ball = __ballot((a0 == m) || (a1 == m));
      int first = __ffsll(ball) - 1;
      if (lane == first){
        if (a0 == m) a0 = NEGINF; else a1 = NEGINF;
      }
    }

    float e0 = (v0 >= thresh) ? expf(v0 - m0v) : 0.f;
    float e1 = 0.f;
    if (lane < 32 && v1 >= thresh) e1 = expf(v1 - m0v);

    float* mrow = out_attn + (size_t)(bt*N_SP + i) * N_SP;
    float num = e0 * mrow[lane];
    if (lane < 32) num += e1 * mrow[64 + lane];
    float den = e0 + e1;
    #pragma unroll
    for (int off = 32; off; off >>= 1){
      den += __shfl_xor(den, off);
      num += __shfl_xor(num, off);
    }
    float inv = 1.0f / den;
    mrow[lane] = e0 * inv;
    if (lane < 32) mrow[64 + lane] = e1 * inv;
    if (lane == 0) out_lr[bt*N_SP + i] = rvec[i] + num * inv;
  }
}

extern "C" void kernel_launch(void* const* d_in, const int* in_sizes, int n_in,
                              void* d_out, int out_size, void* d_ws, size_t ws_size,
                              hipStream_t stream){
  const float* state = (const float*)d_in[0];
  const float* emb   = (const float*)d_in[1];
  const float* qw    = (const float*)d_in[2];
  const float* qb    = (const float*)d_in[3];
  const float* kw    = (const float*)d_in[4];
  const float* kb    = (const float*)d_in[5];
  const float* fc    = (const float*)d_in[6];
  const float* fg    = (const float*)d_in[7];
  const float* har   = (const float*)d_in[8];
  const float* w1    = (const float*)d_in[9];
  const float* b1    = (const float*)d_in[10];
  const float* w2    = (const float*)d_in[11];
  const float* b2    = (const float*)d_in[12];
  const float* w3    = (const float*)d_in[13];
  const float* b3    = (const float*)d_in[14];
  const float* rv    = (const float*)d_in[15];

  float* wsf = (float*)d_ws;
  float* out_lr   = (float*)d_out;
  float* out_attn = out_lr + NBT * N_SP;

  hipLaunchKernelGGL(pre1_kernel, dim3(N_SP), dim3(64), 0, stream,
                     emb, w1, b1, har, wsf);
  hipLaunchKernelGGL(prewg_kernel, dim3(180), dim3(256), 0, stream, fc, fg, wsf);
  hipLaunchKernelGGL(main_kernel, dim3(NBT), dim3(512), 0, stream,
                     state, rv, emb, qw, qb, kw, kb, w1, w2, b2, w3, b3,
                     wsf, out_lr, out_attn);
}

// Round 8
// 198.995 us; speedup vs baseline: 80.6008x; 1.1544x over previous
//
#include <hip/hip_runtime.h>
#include <math.h>

// Problem constants
#define N_SP 96      // NV + NH
#define D_EMB 32
#define H_MLP 32
#define NPAIR 9216   // N*N
#define NBT 512      // B*T
#define HROWS 48     // rows per block (2 blocks per (b,t))

// float workspace offsets (floats)
#define WS_F_EMBI  0         // 96*32 (includes +b1)
#define WS_F_EMBJT 3072      // 32*97 (transposed [u][j], row stride 97)
#define WS_F_ALPHA 6176      // 96
#define WS_F_WG4   6272      // 9216*4  (forms 0-3, interleaved float4 per pair)
#define WS_F_WG1   43136     // 9216    (form 4 coef)

typedef __attribute__((ext_vector_type(8))) short bf16x8;
typedef __attribute__((ext_vector_type(4))) float f32x4;

// Fast gelu (tanh form) via v_exp_f32 + v_rcp_f32 (~3e-4 abs dev; msgs path only)
__device__ __forceinline__ float gelu_fast(float x){
  float x2 = x * x;
  float z  = x * fmaf(x2, -0.1029438824f, -2.3022077325f);
  float e  = __builtin_amdgcn_exp2f(z);
  return x * __builtin_amdgcn_rcpf(1.0f + e);
}

__device__ __forceinline__ short f2bf(float f){
  unsigned u = __builtin_bit_cast(unsigned, f);
  unsigned r = (u + 0x7FFFu + ((u >> 16) & 1u)) >> 16;
  return (short)r;
}

// ---- precompute: emb_i(+b1), emb_jT (stride 97), alpha ----
__global__ void pre1_kernel(const float* __restrict__ emb,
                            const float* __restrict__ w1, const float* __restrict__ b1,
                            const float* __restrict__ har,
                            float* __restrict__ wsf){
  const int n = blockIdx.x;
  const int t = threadIdx.x;           // 64 threads
  const int which = t >> 5, idx = t & 31;
  const float* e = emb + n * D_EMB;
  if (which == 0){
    float acc = b1[idx];
    #pragma unroll
    for (int u = 0; u < D_EMB; u++) acc = fmaf(e[u], w1[(2+u)*H_MLP + idx], acc);
    wsf[WS_F_EMBI + n*H_MLP + idx] = acc;
  } else {
    float acc = 0.f;
    #pragma unroll
    for (int u = 0; u < D_EMB; u++) acc = fmaf(e[u], w1[(2+D_EMB+u)*H_MLP + idx], acc);
    wsf[WS_F_EMBJT + idx*97 + n] = acc;   // transposed store [u][j], stride 97
  }
  if (t == 0){
    float h = har[n];
    float sp = (h > 20.f) ? h : log1pf(expf(h));
    wsf[WS_F_ALPHA + n] = sp + 0.01f;
  }
}

// ---- precompute wg = form_coefs * sigmoid(gates), repacked ----
__global__ void prewg_kernel(const float* __restrict__ fc, const float* __restrict__ fg,
                             float* __restrict__ wsf){
  int idx = blockIdx.x * 256 + threadIdx.x;
  if (idx < 5 * NPAIR){
    float g = 1.f / (1.f + expf(-fg[idx]));
    float v = fc[idx] * g;
    int f = idx / NPAIR;
    int p = idx - f * NPAIR;
    if (f < 4) wsf[WS_F_WG4 + 4*p + f] = v;
    else       wsf[WS_F_WG1 + p] = v;
  }
}

// Emulate numpy einsum f32 dot (SSE baseline, mul+add, 4x unroll, ascending
// chain), horizontal (acc0+acc1)+(acc2+acc3), then f32 division by sqrt(32).
// DO NOT TOUCH arithmetic — bit-matched to the np reference (topk razor rows).
// Low-liveness form: identical rounding sequence to the 2-pass version.
__device__ __forceinline__ float np_score(const float* __restrict__ qi,
                                          const float* __restrict__ kT, int j){
  float acc[4];
  #pragma unroll
  for (int l = 0; l < 4; l++){
    float t = __fadd_rn(__fmul_rn(qi[4+l],  kT[(4+l)*97 + j]),
                        __fmul_rn(qi[l],    kT[(l)*97 + j]));
    t = __fadd_rn(__fmul_rn(qi[8+l],  kT[(8+l)*97 + j]), t);
    t = __fadd_rn(__fmul_rn(qi[12+l], kT[(12+l)*97 + j]), t);
    t = __fadd_rn(__fmul_rn(qi[16+l], kT[(16+l)*97 + j]), t);
    t = __fadd_rn(__fmul_rn(qi[20+l], kT[(20+l)*97 + j]), t);
    t = __fadd_rn(__fmul_rn(qi[24+l], kT[(24+l)*97 + j]), t);
    t = __fadd_rn(__fmul_rn(qi[28+l], kT[(28+l)*97 + j]), t);
    acc[l] = t;
  }
  float s01 = __fadd_rn(acc[0], acc[1]);
  float s23 = __fadd_rn(acc[2], acc[3]);
  return __fdiv_rn(__fadd_rn(s01, s23), 5.65685424949238019521f);
}

// ---- main: 2 blocks per (b,t); block handles 48 i-rows ----
__global__ __launch_bounds__(512, 6) void main_kernel(
    const float* __restrict__ state, const float* __restrict__ rvec,
    const float* __restrict__ emb,
    const float* __restrict__ qwg, const float* __restrict__ qbg,
    const float* __restrict__ kwg, const float* __restrict__ kbg,
    const float* __restrict__ w1, const float* __restrict__ w2g,
    const float* __restrict__ b2g, const float* __restrict__ w3g,
    const float* __restrict__ b3g,
    const float* __restrict__ wsf,
    float* __restrict__ out_lr, float* __restrict__ out_attn){

  __shared__ __align__(16) float s_embi[HROWS*H_MLP];   // own rows only
  __shared__ float s_embjT[H_MLP*97];                   // [u][j], stride 97
  __shared__ __align__(16) float s_q[HROWS*D_EMB];      // own rows only
  __shared__ float s_kT[D_EMB*97];                      // [d][n], all n
  __shared__ float s_x[N_SP], s_hol[N_SP];
  __shared__ float s_wxi[H_MLP], s_wxj[H_MLP], s_b2[H_MLP], s_w3[H_MLP];

  const int tid  = threadIdx.x;
  const int bt   = blockIdx.x >> 1;
  const int roff = (blockIdx.x & 1) * HROWS;
  const int wave = tid >> 6, lane = tid & 63;

  for (int idx = tid; idx < HROWS*H_MLP; idx += 512)
    s_embi[idx] = wsf[WS_F_EMBI + roff*H_MLP + idx];
  for (int idx = tid; idx < H_MLP*97; idx += 512)
    s_embjT[idx] = wsf[WS_F_EMBJT + idx];
  if (tid < N_SP){
    float x = state[bt*N_SP + tid];
    s_x[tid] = x;
    float al = wsf[WS_F_ALPHA + tid];
    s_hol[tid] = x / (1.f + al * x);
  }
  if (tid >= 128 && tid < 160){
    int u = tid - 128;
    s_wxi[u] = w1[u];
    s_wxj[u] = w1[H_MLP + u];
    s_b2[u]  = b2g[u];
    s_w3[u]  = w3g[u];
  }
  __syncthreads();

  // Phase 0 (bit-exact feed of phase 2): kT for ALL n; q for own rows.
  for (int t = tid; t < N_SP*D_EMB; t += 512){
    const int n = t >> 5, d2 = t & 31;
    const float* e = emb + n*D_EMB;
    float ak = __fmul_rn(s_x[n], kwg[d2]);
    #pragma unroll
    for (int u = 0; u < D_EMB; u++)
      ak = fmaf(e[u], kwg[(1+u)*D_EMB + d2], ak);
    ak = __fadd_rn(ak, kbg[d2]);
    s_kT[d2*97 + n] = ak;
  }
  for (int t = tid; t < HROWS*D_EMB; t += 512){
    const int nl = t >> 5, d2 = t & 31;
    const int n  = roff + nl;
    const float* e = emb + n*D_EMB;
    float aq = __fmul_rn(s_x[n], qwg[d2]);
    #pragma unroll
    for (int u = 0; u < D_EMB; u++)
      aq = fmaf(e[u], qwg[(1+u)*D_EMB + d2], aq);
    aq = __fadd_rn(aq, qbg[d2]);
    s_q[t] = aq;
  }

  const float b3v = b3g[0];
  const float* wg4 = wsf + WS_F_WG4;
  const float* wg1 = wsf + WS_F_WG1;
  float* g_ms = out_attn + (size_t)bt * NPAIR;   // msgs staged in attn output

  // w2^T as MFMA A-operand fragments. A[row=unit l15][k=kb+e] = w2[k][unit].
  const int l15 = lane & 15;
  const int g16 = lane >> 4;
  const int kb  = g16 * 8;
  bf16x8 w2f0, w2f1;
  #pragma unroll
  for (int e = 0; e < 8; e++){
    w2f0[e] = f2bf(w2g[(kb+e)*H_MLP + l15]);
    w2f1[e] = f2bf(w2g[(kb+e)*H_MLP + 16 + l15]);
  }
  float b2a[4], b2b[4], w3a[4], w3b[4];
  #pragma unroll
  for (int r = 0; r < 4; r++){
    b2a[r] = s_b2[4*g16 + r];      b2b[r] = s_b2[16 + 4*g16 + r];
    w3a[r] = s_w3[4*g16 + r];      w3b[r] = s_w3[16 + 4*g16 + r];
  }
  float wi[8], wj[8];
  #pragma unroll
  for (int e = 0; e < 8; e++){ wi[e] = s_wxi[kb+e]; wj[e] = s_wxj[kb+e]; }

  // Phase 1: msgs via transposed-MFMA pairwise MLP. Wave owns 6 local rows.
  for (int ii = 0; ii < 6; ii++){
    const int il = 6*wave + ii;          // local row 0..47
    const int i  = roff + il;
    const float xi = s_x[i];
    float base[8];
    #pragma unroll
    for (int e = 0; e < 8; e++)
      base[e] = fmaf(xi, wi[e], s_embi[il*H_MLP + kb + e]);

    for (int jb = 0; jb < 6; jb++){
      const int j0 = 16*jb;
      const int jl = j0 + l15;
      const float xj = s_x[jl];

      // early loads for the msg tail (hide global latency under MFMA)
      float4 w4v = {0,0,0,0};
      float  w1v = 0.f, xjp = 0.f, hjp = 0.f;
      if (lane < 16){
        const int p = i*N_SP + j0 + lane;
        w4v = *(const float4*)&wg4[4*p];
        w1v = wg1[p];
        xjp = s_x[j0 + lane];
        hjp = s_hol[j0 + lane];
      }

      // h1 fragment (B-operand): lane holds h1[pair=l15][k=kb+e]
      bf16x8 hfrag;
      #pragma unroll
      for (int e = 0; e < 8; e++){
        float pre = fmaf(xj, wj[e], base[e] + s_embjT[(kb+e)*97 + jl]);
        hfrag[e] = f2bf(gelu_fast(pre));
      }

      f32x4 acc0 = {b2a[0], b2a[1], b2a[2], b2a[3]};
      f32x4 acc1 = {b2b[0], b2b[1], b2b[2], b2b[3]};
      acc0 = __builtin_amdgcn_mfma_f32_16x16x32_bf16(w2f0, hfrag, acc0, 0, 0, 0);
      acc1 = __builtin_amdgcn_mfma_f32_16x16x32_bf16(w2f1, hfrag, acc1, 0, 0, 0);

      float part = 0.f;
      #pragma unroll
      for (int r = 0; r < 4; r++) part = fmaf(gelu_fast(acc0[r]), w3a[r], part);
      #pragma unroll
      for (int r = 0; r < 4; r++) part = fmaf(gelu_fast(acc1[r]), w3b[r], part);
      part += __shfl_xor(part, 16);
      part += __shfl_xor(part, 32);

      if (lane < 16){
        const float f4 = part + b3v;
        const float msg = w4v.x * xjp
                        + w4v.y * (xi*xjp)
                        + w4v.z * hjp
                        + w4v.w * (xi*hjp)
                        + w1v   * f4;
        g_ms[i*N_SP + j0 + lane] = msg;
      }
    }
  }
  __syncthreads();   // g_ms visibility across waves within block

  // Phase 2: np-exact scores -> radix-select exact 8th-largest threshold
  // (ballot+popc, no shfl chains) -> softmax normalized by threshold
  // (ratio-invariant) -> aggregate. 2-row ILP.
  const float LOG2E = 1.44269504088896340736f;

  for (int ip = 0; ip < 3; ip++){
    #pragma unroll
    for (int s = 0; s < 2; s++){
      const int i = roff + wave + 16*ip + 8*s;
      const float* qi = s_q + (i - roff)*D_EMB;
      float v0 = np_score(qi, s_kT, lane);
      float v1 = 0.f;
      if (lane < 32) v1 = np_score(qi, s_kT, 64 + lane);

      // monotonic uint keys
      unsigned k0 = __builtin_bit_cast(unsigned, v0);
      k0 = (k0 >> 31) ? ~k0 : (k0 | 0x80000000u);
      unsigned k1 = 0u;
      if (lane < 32){
        unsigned u1 = __builtin_bit_cast(unsigned, v1);
        k1 = (u1 >> 31) ? ~u1 : (u1 | 0x80000000u);
      }

      // exact 8th-largest key via 32-step binary search on bits
      unsigned T = 0u;
      #pragma unroll
      for (int b = 31; b >= 0; --b){
        unsigned Tc = T | (1u << b);
        unsigned long long m0 = __ballot(k0 >= Tc);
        unsigned long long m1 = __ballot(k1 >= Tc);
        int cnt = __popcll(m0) + __popcll(m1);
        if (cnt >= 8) T = Tc;
      }
      unsigned uth = (T >> 31) ? (T ^ 0x80000000u) : ~T;
      const float thrf = __builtin_bit_cast(float, uth);

      float e0 = (k0 >= T) ? __builtin_amdgcn_exp2f(LOG2E*(v0 - thrf)) : 0.f;
      float e1 = 0.f;
      if (lane < 32 && k1 >= T) e1 = __builtin_amdgcn_exp2f(LOG2E*(v1 - thrf));

      float* mrow = out_attn + (size_t)(bt*N_SP + i) * N_SP;
      float num = e0 * mrow[lane];
      if (lane < 32) num += e1 * mrow[64 + lane];
      float den = e0 + e1;
      #pragma unroll
      for (int off = 32; off; off >>= 1){
        den += __shfl_xor(den, off);
        num += __shfl_xor(num, off);
      }
      float inv = 1.0f / den;
      mrow[lane] = e0 * inv;
      if (lane < 32) mrow[64 + lane] = e1 * inv;
      if (lane == 0) out_lr[bt*N_SP + i] = rvec[i] + num * inv;
    }
  }
}

extern "C" void kernel_launch(void* const* d_in, const int* in_sizes, int n_in,
                              void* d_out, int out_size, void* d_ws, size_t ws_size,
                              hipStream_t stream){
  const float* state = (const float*)d_in[0];
  const float* emb   = (const float*)d_in[1];
  const float* qw    = (const float*)d_in[2];
  const float* qb    = (const float*)d_in[3];
  const float* kw    = (const float*)d_in[4];
  const float* kb    = (const float*)d_in[5];
  const float* fc    = (const float*)d_in[6];
  const float* fg    = (const float*)d_in[7];
  const float* har   = (const float*)d_in[8];
  const float* w1    = (const float*)d_in[9];
  const float* b1    = (const float*)d_in[10];
  const float* w2    = (const float*)d_in[11];
  const float* b2    = (const float*)d_in[12];
  const float* w3    = (const float*)d_in[13];
  const float* b3    = (const float*)d_in[14];
  const float* rv    = (const float*)d_in[15];

  float* wsf = (float*)d_ws;
  float* out_lr   = (float*)d_out;
  float* out_attn = out_lr + NBT * N_SP;

  hipLaunchKernelGGL(pre1_kernel, dim3(N_SP), dim3(64), 0, stream,
                     emb, w1, b1, har, wsf);
  hipLaunchKernelGGL(prewg_kernel, dim3(180), dim3(256), 0, stream, fc, fg, wsf);
  hipLaunchKernelGGL(main_kernel, dim3(2*NBT), dim3(512), 0, stream,
                     state, rv, emb, qw, qb, kw, kb, w1, w2, b2, w3, b3,
                     wsf, out_lr, out_attn);
}